// Round 18
// baseline (335.853 us; speedup 1.0000x reference)
//
#include <hip/hip_runtime.h>

#define NODE_DIM 128
#define NUM_IRREPS 224
#define SPH_DIM 480
#define HIDDEN 576   // NODE_DIM + 2*NUM_IRREPS
#define NUM_BASIS 20
#define N_NODES 10000
#define N_EDGES 160000
#define NPB 4        // nodes per block in fused MLP
#define EB 16        // edges per window
#define NWIN (N_EDGES / EB)   // 10000 dense windows
#define NT 36        // N-tiles (576/16)
#define IRP 233      // pair row stride in words (odd)
#define SCP 138      // scal row stride in shorts
#define PROW 608     // partial row: 128 scal + 480 sph (bf16)
#define MAXP 20480   // >= nodes + window crossings (<= 19999)
#define PREP_BLOCKS 625
#define MLP_BLOCKS ((N_NODES + NPB - 1) / NPB)

typedef __attribute__((ext_vector_type(8))) short short8v;   // 8 bf16
typedef __attribute__((ext_vector_type(4))) float f32x4;

__device__ __forceinline__ unsigned short f2bf(float f) {
    unsigned int u = __builtin_bit_cast(unsigned int, f);
    u = (u + 0x7fff + ((u >> 16) & 1)) >> 16;   // RNE
    return (unsigned short)u;
}
__device__ __forceinline__ float bf2f(unsigned short h) {
    unsigned int u = ((unsigned int)h) << 16;
    return __builtin_bit_cast(float, u);
}
__device__ __forceinline__ int gate_of(int d) {
    return (d < 128) ? d : (d < 320) ? (128 + (d - 128) / 3) : (192 + (d - 320) / 5);
}

// ---------------- fused prep (histogram + bfrag) + node MLP ----------------
__global__ __launch_bounds__(256) void prep_mlp_kernel(
    const float* __restrict__ xs,
    const int* __restrict__ eidx, int* __restrict__ counts,
    const float* __restrict__ Wr, unsigned short* __restrict__ bfrag,
    const float* __restrict__ W1, const float* __restrict__ b1,
    const float* __restrict__ W2, const float* __restrict__ b2,
    unsigned short* __restrict__ so_bf)
{
    const int t = threadIdx.x;
    if (blockIdx.x < PREP_BLOCKS) {
        const int gt = blockIdx.x * 256 + t;
        if (gt < N_EDGES) atomicAdd(&counts[eidx[gt]], 1);
        if (blockIdx.x == PREP_BLOCKS - 1) {
            for (int idx = t; idx < NT * 64; idx += 256) {
                const int nt = idx >> 6, l = idx & 63;
                const int col = nt * 16 + (l & 15);
                const int kb = (l >> 4) * 8;
                #pragma unroll
                for (int j = 0; j < 8; ++j) {
                    const int k = kb + j;
                    bfrag[(size_t)idx * 8 + j] = (k < NUM_BASIS) ? f2bf(Wr[k * HIDDEN + col]) : (unsigned short)0;
                }
            }
        }
        return;
    }
    // ---- node MLP: 256 threads, 4 nodes/block ----
    __shared__ float xsm[NPB][NODE_DIM];
    __shared__ float hsm[NPB][NODE_DIM];
    const int n0 = (blockIdx.x - PREP_BLOCKS) * NPB;
    const int half = t >> 7;
    const int tc = t & 127;

    #pragma unroll
    for (int i = 0; i < 2; ++i) {
        const int nn = 2 * half + i;
        const int node = n0 + nn;
        xsm[nn][tc] = (node < N_NODES) ? xs[(size_t)node * NODE_DIM + tc] : 0.f;
    }
    __syncthreads();

    float acc[2] = {b1[tc], b1[tc]};
    for (int k = 0; k < NODE_DIM; ++k) {
        const float w = W1[k * NODE_DIM + tc];
        #pragma unroll
        for (int i = 0; i < 2; ++i) acc[i] = fmaf(xsm[2 * half + i][k], w, acc[i]);
    }
    #pragma unroll
    for (int i = 0; i < 2; ++i) {
        const float v = acc[i];
        hsm[2 * half + i][tc] = v / (1.f + __expf(-v));
    }
    __syncthreads();

    for (int j = t; j < HIDDEN; j += 256) {
        float a2[NPB];
        #pragma unroll
        for (int n = 0; n < NPB; ++n) a2[n] = b2[j];
        for (int k = 0; k < NODE_DIM; ++k) {
            const float w = W2[k * HIDDEN + j];
            #pragma unroll
            for (int n = 0; n < NPB; ++n) a2[n] = fmaf(hsm[n][k], w, a2[n]);
        }
        #pragma unroll
        for (int n = 0; n < NPB; ++n) {
            const int node = n0 + n;
            if (node < N_NODES) so_bf[(size_t)node * HIDDEN + j] = f2bf(a2[n]);
        }
    }
}

// ---------------- scan: off = prefix(deg); pairbase = prefix(windows-touched) ----------------
__global__ __launch_bounds__(1024) void scan_kernel(const int* __restrict__ counts,
                                                    int* __restrict__ offsets,
                                                    int* __restrict__ cursor,
                                                    int* __restrict__ pairbase) {
    __shared__ int wsum[16];
    const int tid = threadIdx.x;
    const int lane = tid & 63, w = tid >> 6;
    int deg[10], vals[10];

    // ---- pass 1: scan degrees -> offsets ----
    int run = 0;
    #pragma unroll
    for (int i = 0; i < 10; ++i) {
        int idx = tid * 10 + i;
        deg[i] = (idx < N_NODES) ? counts[idx] : 0;
        vals[i] = run;
        run += deg[i];
    }
    int inc = run;
    #pragma unroll
    for (int off = 1; off < 64; off <<= 1) {
        int v = __shfl_up(inc, off);
        if (lane >= off) inc += v;
    }
    if (lane == 63) wsum[w] = inc;
    __syncthreads();
    if (w == 0) {
        int v = (lane < 16) ? wsum[lane] : 0;
        #pragma unroll
        for (int off = 1; off < 16; off <<= 1) {
            int u = __shfl_up(v, off);
            if (lane >= off) v += u;
        }
        if (lane < 16) wsum[lane] = v;
    }
    __syncthreads();
    const int wbase = (w > 0) ? wsum[w - 1] : 0;
    const int base = wbase + inc - run;
    int off_n[10];
    #pragma unroll
    for (int i = 0; i < 10; ++i) {
        int idx = tid * 10 + i;
        off_n[i] = base + vals[i];
        if (idx < N_NODES) {
            offsets[idx] = off_n[i];
            cursor[idx] = off_n[i];
        }
    }
    if (tid == 1023) offsets[N_NODES] = wbase + inc;
    __syncthreads();

    // ---- pass 2: scan windows-touched -> pairbase ----
    int run2 = 0;
    int vals2[10];
    #pragma unroll
    for (int i = 0; i < 10; ++i) {
        int wins = (deg[i] > 0) ? (((off_n[i] + deg[i] - 1) >> 4) - (off_n[i] >> 4) + 1) : 0;
        vals2[i] = run2;
        run2 += wins;
    }
    int inc2 = run2;
    #pragma unroll
    for (int off = 1; off < 64; off <<= 1) {
        int v = __shfl_up(inc2, off);
        if (lane >= off) inc2 += v;
    }
    if (lane == 63) wsum[w] = inc2;
    __syncthreads();
    if (w == 0) {
        int v = (lane < 16) ? wsum[lane] : 0;
        #pragma unroll
        for (int off = 1; off < 16; off <<= 1) {
            int u = __shfl_up(v, off);
            if (lane >= off) v += u;
        }
        if (lane < 16) wsum[lane] = v;
    }
    __syncthreads();
    const int wbase2 = (w > 0) ? wsum[w - 1] : 0;
    const int base2 = wbase2 + inc2 - run2;
    #pragma unroll
    for (int i = 0; i < 10; ++i) {
        int idx = tid * 10 + i;
        if (idx < N_NODES) pairbase[idx] = base2 + vals2[i];
    }
    if (tid == 1023) pairbase[N_NODES] = wbase2 + inc2;
}

__global__ __launch_bounds__(256) void scatter_kernel(const int* __restrict__ eidx,
                                                      int* __restrict__ cursor,
                                                      int* __restrict__ edge_order,
                                                      int* __restrict__ edge_src) {
    int i = blockIdx.x * blockDim.x + threadIdx.x;
    if (i < N_EDGES) {
        int s = eidx[i];
        int pos = atomicAdd(&cursor[s], 1);
        edge_order[pos] = i;
        edge_src[pos] = s;
    }
}

// ---------------- edge MFMA kernel: dense 16-edge windows, batched-load phase B ----------------
// Phase A: MFMA filter GEMM, fo -> paired bf16 LDS (same as R13/R17).
// Phase B: ALL xsp/rsh gathers issued branch-free up front (R16's proven
//   pattern -> real ILP); then FMA + rare segmented flush (plain bf16 stores
//   into partials, no atomics).
__global__ __launch_bounds__(256, 4) void edge_mfma(
    const float* __restrict__ xsp,
    const float* __restrict__ rbf, const float* __restrict__ fcut,
    const float* __restrict__ rsh, const int* __restrict__ eidx,
    const unsigned short* __restrict__ bfrag, const float* __restrict__ br,
    const unsigned short* __restrict__ so_bf,
    const int* __restrict__ edge_order, const int* __restrict__ edge_src,
    const int* __restrict__ offsets, const int* __restrict__ pairbase,
    unsigned short* __restrict__ partials)
{
    __shared__ unsigned int   pair_s[EB][IRP];    // 14.9 KB
    __shared__ unsigned short scal_s[EB][SCP];    // 4.4 KB
    __shared__ int   e_s[EB];
    __shared__ int   src_s[EB];
    __shared__ int   dst_s[EB];
    __shared__ int   off_s[EB];
    __shared__ int   pb_s[EB];
    __shared__ float fc_s[EB];

    const int t = threadIdx.x;
    const int win = blockIdx.x;
    const int base = win * EB;
    const int lane = t & 63, w = t >> 6;

    // ---- A-fragment: direct global load (lane l: edge row l&15, k=(l>>4)*8+j) ----
    const int m_row = lane & 15;
    const int kb = (lane >> 4) * 8;
    const int e_row = edge_order[base + m_row];
    short8v a0;
    {
        const float* rrow = rbf + (size_t)e_row * NUM_BASIS;
        #pragma unroll
        for (int j = 0; j < 8; ++j) {
            const int k = kb + j;
            a0[j] = (k < NUM_BASIS) ? (short)f2bf(rrow[k]) : (short)0;
        }
    }

    // ---- stage meta ----
    if (t < EB) {
        int pos = base + t;
        int e = edge_order[pos];
        int s = edge_src[pos];
        e_s[t]   = e;
        src_s[t] = s;
        dst_s[t] = eidx[N_EDGES + e];
        fc_s[t]  = fcut[e];
        off_s[t] = offsets[s];
        pb_s[t]  = pairbase[s];
    }
    __syncthreads();

    // ---- phase A: 9 N-tiles per wave ----
    {
        const int rbase = (lane >> 4) * 4;
        int   dA[4];
        float fA[4];
        #pragma unroll
        for (int r = 0; r < 4; ++r) { dA[r] = dst_s[rbase + r]; fA[r] = fc_s[rbase + r]; }
        #pragma unroll
        for (int i = 0; i < NT / 4; ++i) {
            const int nt = w * (NT / 4) + i;
            const short8v bf = *(const short8v*)(bfrag + (size_t)(nt * 64 + lane) * 8);
            f32x4 c0 = {0.f, 0.f, 0.f, 0.f};
            c0 = __builtin_amdgcn_mfma_f32_16x16x32_bf16(a0, bf, c0, 0, 0, 0);
            const int col = nt * 16 + (lane & 15);
            const float brc = br[col];
            #pragma unroll
            for (int r = 0; r < 4; ++r) {
                const int row = rbase + r;
                const float sov = bf2f(so_bf[(size_t)dA[r] * HIDDEN + col]);
                const float v = (c0[r] + brc) * fA[r] * sov;
                const unsigned short hv = f2bf(v);
                if (col < NUM_IRREPS) {
                    ((unsigned short*)&pair_s[row][col])[0] = hv;              // state (lo)
                } else if (col < 2 * NUM_IRREPS) {
                    ((unsigned short*)&pair_s[row][col - NUM_IRREPS])[1] = hv; // edge (hi)
                } else {
                    scal_s[row][col - 2 * NUM_IRREPS] = hv;
                }
            }
        }
    }
    __syncthreads();

    // ---- phase B: batched branch-free loads (R16 pattern), then FMA + rare flush ----
    const bool sphOn = (t < 240);
    const int d0 = 2 * t;
    const int g0 = sphOn ? gate_of(d0) : 0;
    const int g1 = sphOn ? gate_of(d0 + 1) : 0;

    float2 xv[EB], rv[EB];
    if (sphOn) {
        #pragma unroll
        for (int le = 0; le < EB; ++le) {
            xv[le] = *(const float2*)(xsp + (size_t)dst_s[le] * SPH_DIM + d0);
            rv[le] = *(const float2*)(rsh + (size_t)e_s[le]  * SPH_DIM + d0);
        }
    }

    float accS = 0.f, accD0 = 0.f, accD1 = 0.f;
    int cur = 0;   // segment start (local index)

    #pragma unroll
    for (int le = 0; le < EB; ++le) {
        if (src_s[le] != src_s[cur]) {   // block-uniform, rare (~1-2 per window)
            const int prow = pb_s[cur] + (win - (off_s[cur] >> 4));
            unsigned short* pr = partials + (size_t)prow * PROW;
            if (t < 128) pr[t] = f2bf(accS);
            if (sphOn) {
                pr[NODE_DIM + d0]     = f2bf(accD0);
                pr[NODE_DIM + d0 + 1] = f2bf(accD1);
            }
            accD0 = accD1 = accS = 0.f;
            cur = le;
        }
        if (sphOn) {
            const unsigned int p0 = pair_s[le][g0];
            const unsigned int p1 = pair_s[le][g1];
            accD0 = fmaf(xv[le].x, bf2f((unsigned short)(p0 & 0xffffu)),
                    fmaf(rv[le].x, bf2f((unsigned short)(p0 >> 16)), accD0));
            accD1 = fmaf(xv[le].y, bf2f((unsigned short)(p1 & 0xffffu)),
                    fmaf(rv[le].y, bf2f((unsigned short)(p1 >> 16)), accD1));
        }
        if (t < 128) accS += bf2f(scal_s[le][t]);
    }
    {
        const int prow = pb_s[cur] + (win - (off_s[cur] >> 4));
        unsigned short* pr = partials + (size_t)prow * PROW;
        if (t < 128) pr[t] = f2bf(accS);
        if (sphOn) {
            pr[NODE_DIM + d0]     = f2bf(accD0);
            pr[NODE_DIM + d0 + 1] = f2bf(accD1);
        }
    }
}

// ---------------- finalize: out = x + sum(partial rows) ----------------
__global__ __launch_bounds__(256) void finalize_kernel(
    const float* __restrict__ xs, const float* __restrict__ xsp,
    const unsigned short* __restrict__ partials,
    const int* __restrict__ pairbase,
    float* __restrict__ out_scalar, float* __restrict__ out_sph)
{
    const int t = threadIdx.x;
    const int n = blockIdx.x;
    const int pb = pairbase[n], pe = pairbase[n + 1];
    const bool sphOn = (t < 240);
    const int d0 = 2 * t;

    float accS = 0.f, a0 = 0.f, a1 = 0.f;
    for (int p = pb; p < pe; ++p) {
        const unsigned short* pr = partials + (size_t)p * PROW;
        if (t < 128) accS += bf2f(pr[t]);
        if (sphOn) {
            a0 += bf2f(pr[NODE_DIM + d0]);
            a1 += bf2f(pr[NODE_DIM + d0 + 1]);
        }
    }
    if (t < 128)
        out_scalar[(size_t)n * NODE_DIM + t] = xs[(size_t)n * NODE_DIM + t] + accS;
    if (sphOn) {
        const float2 xv = *(const float2*)(xsp + (size_t)n * SPH_DIM + d0);
        float2 o; o.x = xv.x + a0; o.y = xv.y + a1;
        *(float2*)(out_sph + (size_t)n * SPH_DIM + d0) = o;
    }
}

extern "C" void kernel_launch(void* const* d_in, const int* in_sizes, int n_in,
                              void* d_out, int out_size, void* d_ws, size_t ws_size,
                              hipStream_t stream) {
    const float* x_scalar    = (const float*)d_in[0];
    const float* x_spherical = (const float*)d_in[1];
    const float* rbf         = (const float*)d_in[2];
    const float* fcut        = (const float*)d_in[3];
    const float* rsh         = (const float*)d_in[4];
    const int*   eidx        = (const int*)d_in[5];
    const float* W1          = (const float*)d_in[6];
    const float* b1          = (const float*)d_in[7];
    const float* W2          = (const float*)d_in[8];
    const float* b2          = (const float*)d_in[9];
    const float* Wr          = (const float*)d_in[10];
    const float* br          = (const float*)d_in[11];

    float* out        = (float*)d_out;
    float* out_scalar = out;                                   // (N_NODES, 128)
    float* out_sph    = out + (size_t)N_NODES * NODE_DIM;      // (N_NODES, 480)

    // workspace layout
    unsigned short* so_bf = (unsigned short*)d_ws;             // 10000*576 bf16
    unsigned short* partials = so_bf + (size_t)N_NODES * HIDDEN;          // MAXP*608 bf16
    int*   counts     = (int*)(partials + (size_t)MAXP * PROW);
    int*   offsets    = counts + N_NODES;                      // 10001
    int*   pairbase   = offsets + N_NODES + 1;                 // 10001
    int*   cursor     = pairbase + N_NODES + 1;                // 10000
    int*   edge_order = cursor + N_NODES;                      // 160000
    int*   edge_src   = edge_order + N_EDGES;                  // 160000
    unsigned short* bfrag = (unsigned short*)((((uintptr_t)(edge_src + N_EDGES)) + 15) & ~(uintptr_t)15);

    hipMemsetAsync(counts, 0, N_NODES * sizeof(int), stream);
    prep_mlp_kernel<<<PREP_BLOCKS + MLP_BLOCKS, 256, 0, stream>>>(
        x_scalar, eidx, counts, Wr, bfrag, W1, b1, W2, b2, so_bf);
    scan_kernel<<<1, 1024, 0, stream>>>(counts, offsets, cursor, pairbase);
    scatter_kernel<<<(N_EDGES + 255) / 256, 256, 0, stream>>>(eidx, cursor, edge_order, edge_src);
    edge_mfma<<<NWIN, 256, 0, stream>>>(x_spherical, rbf, fcut, rsh, eidx,
                                        bfrag, br, so_bf, edge_order, edge_src,
                                        offsets, pairbase, partials);
    finalize_kernel<<<N_NODES, 256, 0, stream>>>(x_scalar, x_spherical, partials, pairbase,
                                                 out_scalar, out_sph);
}

// Round 19
// 287.929 us; speedup vs baseline: 1.1664x; 1.1664x over previous
//
#include <hip/hip_runtime.h>

#define NODE_DIM 128
#define NUM_IRREPS 224
#define SPH_DIM 480
#define HIDDEN 576   // NODE_DIM + 2*NUM_IRREPS
#define NUM_BASIS 20
#define N_NODES 10000
#define N_EDGES 160000
#define NPB 4        // nodes per block in fused MLP
#define EB 16        // edges per window
#define NWIN (N_EDGES / EB)   // 10000 dense windows
#define NT 36        // N-tiles (576/16)
#define IRP 233      // pair row stride in words (odd)
#define SCP 138      // scal row stride in shorts
#define PROW 608     // partial row: 128 scal + 480 sph (bf16)
#define MAXP 20480   // >= nodes + window crossings (<= 19999)
#define PREP_BLOCKS 625
#define MLP_BLOCKS ((N_NODES + NPB - 1) / NPB)

typedef __attribute__((ext_vector_type(8))) short short8v;   // 8 bf16
typedef __attribute__((ext_vector_type(4))) float f32x4;

__device__ __forceinline__ unsigned short f2bf(float f) {
    unsigned int u = __builtin_bit_cast(unsigned int, f);
    u = (u + 0x7fff + ((u >> 16) & 1)) >> 16;   // RNE
    return (unsigned short)u;
}
__device__ __forceinline__ float bf2f(unsigned short h) {
    unsigned int u = ((unsigned int)h) << 16;
    return __builtin_bit_cast(float, u);
}
__device__ __forceinline__ int gate_of(int d) {
    return (d < 128) ? d : (d < 320) ? (128 + (d - 128) / 3) : (192 + (d - 320) / 5);
}

// ---------------- fused prep (histogram + bfrag) + node MLP ----------------
__global__ __launch_bounds__(256) void prep_mlp_kernel(
    const float* __restrict__ xs,
    const int* __restrict__ eidx, int* __restrict__ counts,
    const float* __restrict__ Wr, unsigned short* __restrict__ bfrag,
    const float* __restrict__ W1, const float* __restrict__ b1,
    const float* __restrict__ W2, const float* __restrict__ b2,
    unsigned short* __restrict__ so_bf)
{
    const int t = threadIdx.x;
    if (blockIdx.x < PREP_BLOCKS) {
        const int gt = blockIdx.x * 256 + t;
        if (gt < N_EDGES) atomicAdd(&counts[eidx[gt]], 1);
        if (blockIdx.x == PREP_BLOCKS - 1) {
            for (int idx = t; idx < NT * 64; idx += 256) {
                const int nt = idx >> 6, l = idx & 63;
                const int col = nt * 16 + (l & 15);
                const int kb = (l >> 4) * 8;
                #pragma unroll
                for (int j = 0; j < 8; ++j) {
                    const int k = kb + j;
                    bfrag[(size_t)idx * 8 + j] = (k < NUM_BASIS) ? f2bf(Wr[k * HIDDEN + col]) : (unsigned short)0;
                }
            }
        }
        return;
    }
    // ---- node MLP: 256 threads, 4 nodes/block ----
    __shared__ float xsm[NPB][NODE_DIM];
    __shared__ float hsm[NPB][NODE_DIM];
    const int n0 = (blockIdx.x - PREP_BLOCKS) * NPB;
    const int half = t >> 7;
    const int tc = t & 127;

    #pragma unroll
    for (int i = 0; i < 2; ++i) {
        const int nn = 2 * half + i;
        const int node = n0 + nn;
        xsm[nn][tc] = (node < N_NODES) ? xs[(size_t)node * NODE_DIM + tc] : 0.f;
    }
    __syncthreads();

    float acc[2] = {b1[tc], b1[tc]};
    for (int k = 0; k < NODE_DIM; ++k) {
        const float w = W1[k * NODE_DIM + tc];
        #pragma unroll
        for (int i = 0; i < 2; ++i) acc[i] = fmaf(xsm[2 * half + i][k], w, acc[i]);
    }
    #pragma unroll
    for (int i = 0; i < 2; ++i) {
        const float v = acc[i];
        hsm[2 * half + i][tc] = v / (1.f + __expf(-v));
    }
    __syncthreads();

    for (int j = t; j < HIDDEN; j += 256) {
        float a2[NPB];
        #pragma unroll
        for (int n = 0; n < NPB; ++n) a2[n] = b2[j];
        for (int k = 0; k < NODE_DIM; ++k) {
            const float w = W2[k * HIDDEN + j];
            #pragma unroll
            for (int n = 0; n < NPB; ++n) a2[n] = fmaf(hsm[n][k], w, a2[n]);
        }
        #pragma unroll
        for (int n = 0; n < NPB; ++n) {
            const int node = n0 + n;
            if (node < N_NODES) so_bf[(size_t)node * HIDDEN + j] = f2bf(a2[n]);
        }
    }
}

// ---------------- scan: off = prefix(deg); pairbase = prefix(windows-touched) ----------------
__global__ __launch_bounds__(1024) void scan_kernel(const int* __restrict__ counts,
                                                    int* __restrict__ offsets,
                                                    int* __restrict__ cursor,
                                                    int* __restrict__ pairbase) {
    __shared__ int wsum[16];
    const int tid = threadIdx.x;
    const int lane = tid & 63, w = tid >> 6;
    int deg[10], vals[10];

    int run = 0;
    #pragma unroll
    for (int i = 0; i < 10; ++i) {
        int idx = tid * 10 + i;
        deg[i] = (idx < N_NODES) ? counts[idx] : 0;
        vals[i] = run;
        run += deg[i];
    }
    int inc = run;
    #pragma unroll
    for (int off = 1; off < 64; off <<= 1) {
        int v = __shfl_up(inc, off);
        if (lane >= off) inc += v;
    }
    if (lane == 63) wsum[w] = inc;
    __syncthreads();
    if (w == 0) {
        int v = (lane < 16) ? wsum[lane] : 0;
        #pragma unroll
        for (int off = 1; off < 16; off <<= 1) {
            int u = __shfl_up(v, off);
            if (lane >= off) v += u;
        }
        if (lane < 16) wsum[lane] = v;
    }
    __syncthreads();
    const int wbase = (w > 0) ? wsum[w - 1] : 0;
    const int base = wbase + inc - run;
    int off_n[10];
    #pragma unroll
    for (int i = 0; i < 10; ++i) {
        int idx = tid * 10 + i;
        off_n[i] = base + vals[i];
        if (idx < N_NODES) {
            offsets[idx] = off_n[i];
            cursor[idx] = off_n[i];
        }
    }
    if (tid == 1023) offsets[N_NODES] = wbase + inc;
    __syncthreads();

    int run2 = 0;
    int vals2[10];
    #pragma unroll
    for (int i = 0; i < 10; ++i) {
        int wins = (deg[i] > 0) ? (((off_n[i] + deg[i] - 1) >> 4) - (off_n[i] >> 4) + 1) : 0;
        vals2[i] = run2;
        run2 += wins;
    }
    int inc2 = run2;
    #pragma unroll
    for (int off = 1; off < 64; off <<= 1) {
        int v = __shfl_up(inc2, off);
        if (lane >= off) inc2 += v;
    }
    if (lane == 63) wsum[w] = inc2;
    __syncthreads();
    if (w == 0) {
        int v = (lane < 16) ? wsum[lane] : 0;
        #pragma unroll
        for (int off = 1; off < 16; off <<= 1) {
            int u = __shfl_up(v, off);
            if (lane >= off) v += u;
        }
        if (lane < 16) wsum[lane] = v;
    }
    __syncthreads();
    const int wbase2 = (w > 0) ? wsum[w - 1] : 0;
    const int base2 = wbase2 + inc2 - run2;
    #pragma unroll
    for (int i = 0; i < 10; ++i) {
        int idx = tid * 10 + i;
        if (idx < N_NODES) pairbase[idx] = base2 + vals2[i];
    }
    if (tid == 1023) pairbase[N_NODES] = wbase2 + inc2;
}

__global__ __launch_bounds__(256) void scatter_kernel(const int* __restrict__ eidx,
                                                      int* __restrict__ cursor,
                                                      int* __restrict__ edge_order,
                                                      int* __restrict__ edge_src) {
    int i = blockIdx.x * blockDim.x + threadIdx.x;
    if (i < N_EDGES) {
        int s = eidx[i];
        int pos = atomicAdd(&cursor[s], 1);
        edge_order[pos] = i;
        edge_src[pos] = s;
    }
}

// ---------------- edge MFMA kernel: dense windows, FORCED batched phase B ----------------
// Phase B: 2 groups of 8 edges. Each group issues 16 float2 loads into NAMED
// scalars, then an asm memory fence makes load-sinking illegal, then consumes.
__global__ __launch_bounds__(256, 4) void edge_mfma(
    const float* __restrict__ xsp,
    const float* __restrict__ rbf, const float* __restrict__ fcut,
    const float* __restrict__ rsh, const int* __restrict__ eidx,
    const unsigned short* __restrict__ bfrag, const float* __restrict__ br,
    const unsigned short* __restrict__ so_bf,
    const int* __restrict__ edge_order, const int* __restrict__ edge_src,
    const int* __restrict__ offsets, const int* __restrict__ pairbase,
    unsigned short* __restrict__ partials)
{
    __shared__ unsigned int   pair_s[EB][IRP];    // 14.9 KB
    __shared__ unsigned short scal_s[EB][SCP];    // 4.4 KB
    __shared__ int   e_s[EB];
    __shared__ int   src_s[EB];
    __shared__ int   dst_s[EB];
    __shared__ int   off_s[EB];
    __shared__ int   pb_s[EB];
    __shared__ float fc_s[EB];

    const int t = threadIdx.x;
    const int win = blockIdx.x;
    const int base = win * EB;
    const int lane = t & 63, w = t >> 6;

    // ---- A-fragment ----
    const int m_row = lane & 15;
    const int kb = (lane >> 4) * 8;
    const int e_row = edge_order[base + m_row];
    short8v a0;
    {
        const float* rrow = rbf + (size_t)e_row * NUM_BASIS;
        #pragma unroll
        for (int j = 0; j < 8; ++j) {
            const int k = kb + j;
            a0[j] = (k < NUM_BASIS) ? (short)f2bf(rrow[k]) : (short)0;
        }
    }

    // ---- stage meta ----
    if (t < EB) {
        int pos = base + t;
        int e = edge_order[pos];
        int s = edge_src[pos];
        e_s[t]   = e;
        src_s[t] = s;
        dst_s[t] = eidx[N_EDGES + e];
        fc_s[t]  = fcut[e];
        off_s[t] = offsets[s];
        pb_s[t]  = pairbase[s];
    }
    __syncthreads();

    // ---- phase A: 9 N-tiles per wave ----
    {
        const int rbase = (lane >> 4) * 4;
        int   dA[4];
        float fA[4];
        #pragma unroll
        for (int r = 0; r < 4; ++r) { dA[r] = dst_s[rbase + r]; fA[r] = fc_s[rbase + r]; }
        #pragma unroll
        for (int i = 0; i < NT / 4; ++i) {
            const int nt = w * (NT / 4) + i;
            const short8v bf = *(const short8v*)(bfrag + (size_t)(nt * 64 + lane) * 8);
            f32x4 c0 = {0.f, 0.f, 0.f, 0.f};
            c0 = __builtin_amdgcn_mfma_f32_16x16x32_bf16(a0, bf, c0, 0, 0, 0);
            const int col = nt * 16 + (lane & 15);
            const float brc = br[col];
            #pragma unroll
            for (int r = 0; r < 4; ++r) {
                const int row = rbase + r;
                const float sov = bf2f(so_bf[(size_t)dA[r] * HIDDEN + col]);
                const float v = (c0[r] + brc) * fA[r] * sov;
                const unsigned short hv = f2bf(v);
                if (col < NUM_IRREPS) {
                    ((unsigned short*)&pair_s[row][col])[0] = hv;              // state (lo)
                } else if (col < 2 * NUM_IRREPS) {
                    ((unsigned short*)&pair_s[row][col - NUM_IRREPS])[1] = hv; // edge (hi)
                } else {
                    scal_s[row][col - 2 * NUM_IRREPS] = hv;
                }
            }
        }
    }
    __syncthreads();

    // ---- phase B: forced-batch, 2 groups of 8 edges ----
    const bool sphOn = (t < 240);
    const int d0 = 2 * t;
    const int g0 = sphOn ? gate_of(d0) : 0;
    const int g1 = sphOn ? gate_of(d0 + 1) : 0;

    float accS = 0.f, accD0 = 0.f, accD1 = 0.f;
    int cur = 0;

#define LOAD1(V, X, LE) \
    float2 X##V = make_float2(0.f, 0.f), R##V = make_float2(0.f, 0.f); \
    if (sphOn) { \
        X##V = *(const float2*)(xsp + (size_t)dst_s[LE] * SPH_DIM + d0); \
        R##V = *(const float2*)(rsh + (size_t)e_s[LE]  * SPH_DIM + d0); \
    }

#define CONS1(V, X, LE) do { \
    if (src_s[LE] != src_s[cur]) { \
        const int prow = pb_s[cur] + (win - (off_s[cur] >> 4)); \
        unsigned short* pr = partials + (size_t)prow * PROW; \
        if (t < 128) pr[t] = f2bf(accS); \
        if (sphOn) { \
            pr[NODE_DIM + d0]     = f2bf(accD0); \
            pr[NODE_DIM + d0 + 1] = f2bf(accD1); \
        } \
        accD0 = accD1 = accS = 0.f; \
        cur = LE; \
    } \
    if (sphOn) { \
        const unsigned int p0 = pair_s[LE][g0]; \
        const unsigned int p1 = pair_s[LE][g1]; \
        accD0 = fmaf(X##V.x, bf2f((unsigned short)(p0 & 0xffffu)), \
                fmaf(R##V.x, bf2f((unsigned short)(p0 >> 16)), accD0)); \
        accD1 = fmaf(X##V.y, bf2f((unsigned short)(p1 & 0xffffu)), \
                fmaf(R##V.y, bf2f((unsigned short)(p1 >> 16)), accD1)); \
    } \
    if (t < 128) accS += bf2f(scal_s[LE][t]); \
} while (0)

    {   // group 0: edges 0..7
        LOAD1(0, X, 0) LOAD1(1, X, 1) LOAD1(2, X, 2) LOAD1(3, X, 3)
        LOAD1(4, X, 4) LOAD1(5, X, 5) LOAD1(6, X, 6) LOAD1(7, X, 7)
        asm volatile("" ::: "memory");   // loads above may not sink below
        CONS1(0, X, 0); CONS1(1, X, 1); CONS1(2, X, 2); CONS1(3, X, 3);
        CONS1(4, X, 4); CONS1(5, X, 5); CONS1(6, X, 6); CONS1(7, X, 7);
    }
    {   // group 1: edges 8..15
        LOAD1(0, Y, 8)  LOAD1(1, Y, 9)  LOAD1(2, Y, 10) LOAD1(3, Y, 11)
        LOAD1(4, Y, 12) LOAD1(5, Y, 13) LOAD1(6, Y, 14) LOAD1(7, Y, 15)
        asm volatile("" ::: "memory");
        CONS1(0, Y, 8);  CONS1(1, Y, 9);  CONS1(2, Y, 10); CONS1(3, Y, 11);
        CONS1(4, Y, 12); CONS1(5, Y, 13); CONS1(6, Y, 14); CONS1(7, Y, 15);
    }

    {   // final flush
        const int prow = pb_s[cur] + (win - (off_s[cur] >> 4));
        unsigned short* pr = partials + (size_t)prow * PROW;
        if (t < 128) pr[t] = f2bf(accS);
        if (sphOn) {
            pr[NODE_DIM + d0]     = f2bf(accD0);
            pr[NODE_DIM + d0 + 1] = f2bf(accD1);
        }
    }
#undef LOAD1
#undef CONS1
}

// ---------------- finalize: out = x + sum(partial rows) ----------------
__global__ __launch_bounds__(256) void finalize_kernel(
    const float* __restrict__ xs, const float* __restrict__ xsp,
    const unsigned short* __restrict__ partials,
    const int* __restrict__ pairbase,
    float* __restrict__ out_scalar, float* __restrict__ out_sph)
{
    const int t = threadIdx.x;
    const int n = blockIdx.x;
    const int pb = pairbase[n], pe = pairbase[n + 1];
    const bool sphOn = (t < 240);
    const int d0 = 2 * t;

    float accS = 0.f, a0 = 0.f, a1 = 0.f;
    for (int p = pb; p < pe; ++p) {
        const unsigned short* pr = partials + (size_t)p * PROW;
        if (t < 128) accS += bf2f(pr[t]);
        if (sphOn) {
            a0 += bf2f(pr[NODE_DIM + d0]);
            a1 += bf2f(pr[NODE_DIM + d0 + 1]);
        }
    }
    if (t < 128)
        out_scalar[(size_t)n * NODE_DIM + t] = xs[(size_t)n * NODE_DIM + t] + accS;
    if (sphOn) {
        const float2 xv = *(const float2*)(xsp + (size_t)n * SPH_DIM + d0);
        float2 o; o.x = xv.x + a0; o.y = xv.y + a1;
        *(float2*)(out_sph + (size_t)n * SPH_DIM + d0) = o;
    }
}

extern "C" void kernel_launch(void* const* d_in, const int* in_sizes, int n_in,
                              void* d_out, int out_size, void* d_ws, size_t ws_size,
                              hipStream_t stream) {
    const float* x_scalar    = (const float*)d_in[0];
    const float* x_spherical = (const float*)d_in[1];
    const float* rbf         = (const float*)d_in[2];
    const float* fcut        = (const float*)d_in[3];
    const float* rsh         = (const float*)d_in[4];
    const int*   eidx        = (const int*)d_in[5];
    const float* W1          = (const float*)d_in[6];
    const float* b1          = (const float*)d_in[7];
    const float* W2          = (const float*)d_in[8];
    const float* b2          = (const float*)d_in[9];
    const float* Wr          = (const float*)d_in[10];
    const float* br          = (const float*)d_in[11];

    float* out        = (float*)d_out;
    float* out_scalar = out;                                   // (N_NODES, 128)
    float* out_sph    = out + (size_t)N_NODES * NODE_DIM;      // (N_NODES, 480)

    // workspace layout
    unsigned short* so_bf = (unsigned short*)d_ws;             // 10000*576 bf16
    unsigned short* partials = so_bf + (size_t)N_NODES * HIDDEN;          // MAXP*608 bf16
    int*   counts     = (int*)(partials + (size_t)MAXP * PROW);
    int*   offsets    = counts + N_NODES;                      // 10001
    int*   pairbase   = offsets + N_NODES + 1;                 // 10001
    int*   cursor     = pairbase + N_NODES + 1;                // 10000
    int*   edge_order = cursor + N_NODES;                      // 160000
    int*   edge_src   = edge_order + N_EDGES;                  // 160000
    unsigned short* bfrag = (unsigned short*)((((uintptr_t)(edge_src + N_EDGES)) + 15) & ~(uintptr_t)15);

    hipMemsetAsync(counts, 0, N_NODES * sizeof(int), stream);
    prep_mlp_kernel<<<PREP_BLOCKS + MLP_BLOCKS, 256, 0, stream>>>(
        x_scalar, eidx, counts, Wr, bfrag, W1, b1, W2, b2, so_bf);
    scan_kernel<<<1, 1024, 0, stream>>>(counts, offsets, cursor, pairbase);
    scatter_kernel<<<(N_EDGES + 255) / 256, 256, 0, stream>>>(eidx, cursor, edge_order, edge_src);
    edge_mfma<<<NWIN, 256, 0, stream>>>(x_spherical, rbf, fcut, rsh, eidx,
                                        bfrag, br, so_bf, edge_order, edge_src,
                                        offsets, pairbase, partials);
    finalize_kernel<<<N_NODES, 256, 0, stream>>>(x_scalar, x_spherical, partials, pairbase,
                                                 out_scalar, out_sph);
}